// Round 1
// baseline (9076.135 us; speedup 1.0000x reference)
//
#include <hip/hip_runtime.h>

#define SEQ  512
#define IDIM 256
#define HD   1024
#define BT   256
#define NCLS 10

#define GRN 32   // row groups (32 rows of H each)
#define GBN 8    // batch groups (32 batch cols each)
#define NWG (GRN*GBN)
#define TPB 256

typedef __attribute__((ext_vector_type(8))) short short8;
typedef __attribute__((ext_vector_type(4))) float f32x4;
typedef __attribute__((ext_vector_type(4))) unsigned short us4;

// h double buffer in MFMA-B fragment order.
// logical h[k][b], k in [0,1024), b in [0,256)
// block = (gb*2+nt), gb=b>>5, nt=(b>>4)&1 ; kk=k>>5
// lane  = (b&15) | (((k>>3)&3)<<4) ; i = k&7
// ushort index = (block*32 + kk)*512 + lane*8 + i
__device__ unsigned short g_h[2][GBN*2*32*64*8];
__device__ float g_hfinal[BT][HD];           // [b][k] fp32 final hidden state
__device__ unsigned int g_cnt[GBN];
__device__ unsigned int g_done[GBN];

__device__ __forceinline__ unsigned short f2bf(float f){
    unsigned int u = __builtin_bit_cast(unsigned int, f);
    u += 0x7fffu + ((u >> 16) & 1u);         // round-to-nearest-even
    return (unsigned short)(u >> 16);
}

__device__ __forceinline__ void group_barrier(int gb, int tid, unsigned target){
    __syncthreads();                          // drains vmcnt for all waves (stores in L2)
    if (tid == 0){
        __threadfence();                      // release: wb L2 so other XCDs see h
        atomicAdd(&g_cnt[gb], 1u);
        int guard = 0;
        while (__hip_atomic_load(&g_cnt[gb], __ATOMIC_ACQUIRE, __HIP_MEMORY_SCOPE_AGENT) < target
               && ++guard < (1 << 20)) { }
        __threadfence();                      // acquire: inv caches before new reads
    }
    __syncthreads();
}

__global__ __launch_bounds__(TPB, 1) void rnn_main(
    const float* __restrict__ x, const float* __restrict__ w_hx,
    const float* __restrict__ w_hh, const float* __restrict__ b_h)
{
    __shared__ unsigned short sAB[2*40*64*8]; // 80 KB: [mt][kk 0..39][lane][8] frag-order

    const int tid = threadIdx.x;
    const int wg  = blockIdx.x;
    const int gr  = wg >> 3;
    const int gb  = wg & 7;
    const int r0  = gr * 32;
    const int b0  = gb * 32;
    const int l   = tid & 63;
    const int wv  = tid >> 6;
    const int mt  = wv >> 1;
    const int nt  = wv & 1;

    // ---- W_hh rows [r0,r0+32) -> frag-order LDS, kk = 0..31
    for (int j = 0; j < 32; ++j){
        int idx = j*TPB + tid;                // 8192 float4 chunks
        int r = idx >> 8;                     // 0..31
        int k = (idx & 255) << 2;             // 0..1023 step 4
        f32x4 v = *(const f32x4*)(w_hh + (size_t)(r0 + r)*HD + k);
        int kk  = k >> 5;
        int ln  = (r & 15) | (((k >> 3) & 3) << 4);
        int mtw = r >> 4;
        us4 u = { f2bf(v[0]), f2bf(v[1]), f2bf(v[2]), f2bf(v[3]) };
        *(us4*)&sAB[ ((mtw*40 + kk)*64 + ln)*8 + (k & 7) ] = u;
    }
    // ---- w_hx rows -> frag-order LDS, kk = 32..39
    for (int j = 0; j < 8; ++j){
        int idx = j*TPB + tid;                // 2048 float4 chunks
        int r = idx >> 6;
        int k = (idx & 63) << 2;
        f32x4 v = *(const f32x4*)(w_hx + (size_t)(r0 + r)*IDIM + k);
        int kk  = 32 + (k >> 5);
        int ln  = (r & 15) | (((k >> 3) & 3) << 4);
        int mtw = r >> 4;
        us4 u = { f2bf(v[0]), f2bf(v[1]), f2bf(v[2]), f2bf(v[3]) };
        *(us4*)&sAB[ ((mtw*40 + kk)*64 + ln)*8 + (k & 7) ] = u;
    }
    // ---- zero our kk=gr slice of h buffer 0 (h_init = 0)
    if (tid < 128){
        int ntz = tid >> 6, lz = tid & 63;
        us4 z = {0,0,0,0};
        size_t base = (((size_t)(gb*2 + ntz)*32 + gr)*64 + lz)*8;
        *(us4*)&g_h[0][base]     = z;
        *(us4*)&g_h[0][base + 4] = z;
    }
    // ---- bias fragment: rows of this lane's C/D slots
    f32x4 bh = *(const f32x4*)(b_h + r0 + mt*16 + ((l >> 4) << 2));

    const float* xlane = x + (size_t)(b0 + nt*16 + (l & 15)) * (SEQ*IDIM) + ((l >> 4) << 3);
    const unsigned short* sA = &sAB[ (size_t)mt * 40 * 512 ];
    const size_t hblk = (size_t)(gb*2 + nt) * 32 * 512;

    unsigned bcnt = 0;
    group_barrier(gb, tid, 32u * ++bcnt);     // init (incl. zeroed buf0) visible

    for (int t = 0; t < SEQ; ++t){
        const int rb = t & 1;
        const unsigned short* hbuf = &g_h[rb][hblk];
        f32x4 acc = bh;
        // recurrent part: K = 1024
        #pragma unroll 8
        for (int kk = 0; kk < 32; ++kk){
            short8 a = *(const short8*)&sA[ (kk*64 + l)*8 ];
            short8 b = *(const short8*)&hbuf[ (kk*64 + l)*8 ];
            acc = __builtin_amdgcn_mfma_f32_16x16x32_bf16(a, b, acc, 0, 0, 0);
        }
        // input part: K = 256, x loaded fp32 -> bf16 on the fly
        const float* xp = xlane + t*IDIM;
        #pragma unroll
        for (int kk = 0; kk < 8; ++kk){
            f32x4 v0 = *(const f32x4*)(xp + kk*32);
            f32x4 v1 = *(const f32x4*)(xp + kk*32 + 4);
            short8 bx;
            bx[0] = (short)f2bf(v0[0]); bx[1] = (short)f2bf(v0[1]);
            bx[2] = (short)f2bf(v0[2]); bx[3] = (short)f2bf(v0[3]);
            bx[4] = (short)f2bf(v1[0]); bx[5] = (short)f2bf(v1[1]);
            bx[6] = (short)f2bf(v1[2]); bx[7] = (short)f2bf(v1[3]);
            short8 a = *(const short8*)&sA[ ((32 + kk)*64 + l)*8 ];
            acc = __builtin_amdgcn_mfma_f32_16x16x32_bf16(a, bx, acc, 0, 0, 0);
        }
        float h0 = tanhf(acc[0]);
        float h1 = tanhf(acc[1]);
        float h2 = tanhf(acc[2]);
        float h3 = tanhf(acc[3]);

        // write h_new tile (rows r0+rloc.., col b0+bloc) in frag order to buf rb^1
        int rloc = mt*16 + ((l >> 4) << 2);   // local row base
        int bloc = nt*16 + (l & 15);          // local col
        int lnp  = (l & 15) | (((rloc >> 3) & 3) << 4);
        us4 hw = { f2bf(h0), f2bf(h1), f2bf(h2), f2bf(h3) };
        size_t widx = (((size_t)(gb*2 + nt)*32 + gr)*64 + lnp)*8 + (rloc & 7);
        *(us4*)&g_h[rb ^ 1][widx] = hw;
        if (t == SEQ-1){
            f32x4 hf = {h0, h1, h2, h3};
            *(f32x4*)&g_hfinal[b0 + bloc][r0 + rloc] = hf;
        }
        group_barrier(gb, tid, 32u * ++bcnt);
    }

    // ---- reset barrier state for next (graph-replayed) launch
    if (tid == 0){
        atomicAdd(&g_done[gb], 1u);
        if (gr == 0){
            int guard = 0;
            while (__hip_atomic_load(&g_done[gb], __ATOMIC_ACQUIRE, __HIP_MEMORY_SCOPE_AGENT) < 32u
                   && ++guard < (1 << 20)) { }
            __hip_atomic_store(&g_cnt[gb],  0u, __ATOMIC_RELAXED, __HIP_MEMORY_SCOPE_AGENT);
            __hip_atomic_store(&g_done[gb], 0u, __ATOMIC_RELAXED, __HIP_MEMORY_SCOPE_AGENT);
        }
    }
}

// p = w_ph @ h_final + b_p ; out[b][c]
__global__ __launch_bounds__(TPB, 1) void proj_kernel(
    const float* __restrict__ w_ph, const float* __restrict__ b_p, float* __restrict__ out)
{
    const int b   = blockIdx.x;
    const int tid = threadIdx.x;
    const int l   = tid & 63;
    const int wv  = tid >> 6;
    __shared__ float red[4];
    f32x4 hv = *(const f32x4*)(&g_hfinal[b][0] + tid*4);
    for (int c = 0; c < NCLS; ++c){
        f32x4 wvv = *(const f32x4*)(w_ph + c*HD + tid*4);
        float s = hv[0]*wvv[0] + hv[1]*wvv[1] + hv[2]*wvv[2] + hv[3]*wvv[3];
        #pragma unroll
        for (int off = 32; off; off >>= 1) s += __shfl_down(s, off, 64);
        if (l == 0) red[wv] = s;
        __syncthreads();
        if (tid == 0) out[b*NCLS + c] = red[0] + red[1] + red[2] + red[3] + b_p[c];
        __syncthreads();
    }
}

extern "C" void kernel_launch(void* const* d_in, const int* in_sizes, int n_in,
                              void* d_out, int out_size, void* d_ws, size_t ws_size,
                              hipStream_t stream) {
    const float* x    = (const float*)d_in[0];
    const float* w_hx = (const float*)d_in[1];
    const float* w_hh = (const float*)d_in[2];
    const float* b_h  = (const float*)d_in[3];
    const float* w_ph = (const float*)d_in[4];
    const float* b_p  = (const float*)d_in[5];

    void* args[] = { (void*)&x, (void*)&w_hx, (void*)&w_hh, (void*)&b_h };
    hipError_t err = hipLaunchCooperativeKernel((void*)rnn_main, dim3(NWG), dim3(TPB),
                                                args, 0, stream);
    if (err != hipSuccess) {
        // fallback: 256 WGs at 1/CU on 256 CUs are naturally co-resident
        rnn_main<<<dim3(NWG), dim3(TPB), 0, stream>>>(x, w_hx, w_hh, b_h);
    }
    proj_kernel<<<dim3(BT), dim3(TPB), 0, stream>>>(w_ph, b_p, (float*)d_out);
}

// Round 2
// 4733.646 us; speedup vs baseline: 1.9174x; 1.9174x over previous
//
#include <hip/hip_runtime.h>

#define SEQ  512
#define IDIM 256
#define HD   1024
#define BT   256
#define NCLS 10

#define GRN 32   // row groups (32 rows of H each)
#define GBN 8    // batch groups (32 batch cols each)
#define NWG (GRN*GBN)
#define TPB 256

typedef __attribute__((ext_vector_type(8))) short short8;
typedef __attribute__((ext_vector_type(4))) float f32x4;
typedef __attribute__((ext_vector_type(4))) unsigned short us4;

// h double buffer in MFMA-B fragment order (same layout as R1).
__device__ unsigned short g_h[2][GBN*2*32*64*8];
__device__ float g_hfinal[BT][HD];           // [b][k] fp32 final hidden state
__device__ int g_flag[GBN][64];              // per-WG arrival flags, 256B per group
__device__ unsigned int g_done[GBN*16];      // padded done counters

__device__ __forceinline__ unsigned short f2bf(float f){
    unsigned int u = __builtin_bit_cast(unsigned int, f);
    u += 0x7fffu + ((u >> 16) & 1u);         // round-to-nearest-even
    return (unsigned short)(u >> 16);
}

// Arrive: drain all waves' stores (syncthreads emits vmcnt(0)), then one
// release store of our own flag. No RMW, no shared-line contention.
__device__ __forceinline__ void arrive(int gb, int gr, int tid, int val){
    __syncthreads();
    if (tid == 0){
        __hip_atomic_store(&g_flag[gb][gr], val, __ATOMIC_RELEASE, __HIP_MEMORY_SCOPE_AGENT);
    }
}

// Wait: wave 0 gathers all 32 flags (one 32-lane load per poll), single
// acquire fence after success, then release the block.
__device__ __forceinline__ void wait_all(int gb, int tid, int val){
    if (tid < 64){
        int idx = tid & 31;
        int guard = 0;
        for (;;){
            int f = __hip_atomic_load(&g_flag[gb][idx], __ATOMIC_RELAXED, __HIP_MEMORY_SCOPE_AGENT);
            if (__all(f >= val)) break;
            if (++guard > (1 << 22)) break;   // hang safety
            __builtin_amdgcn_s_sleep(1);
        }
        __builtin_amdgcn_fence(__ATOMIC_ACQUIRE, "agent");
    }
    __syncthreads();
}

__global__ __launch_bounds__(TPB, 1) void rnn_main(
    const float* __restrict__ x, const float* __restrict__ w_hx,
    const float* __restrict__ w_hh, const float* __restrict__ b_h)
{
    __shared__ unsigned short sAB[2*40*64*8]; // 80 KB frag-order weights

    const int tid = threadIdx.x;
    const int wg  = blockIdx.x;
    const int gr  = wg >> 3;
    const int gb  = wg & 7;   // same-XCD for all 32 members of a group (bid%8 ~ XCD)
    const int r0  = gr * 32;
    const int b0  = gb * 32;
    const int l   = tid & 63;
    const int wv  = tid >> 6;
    const int mt  = wv >> 1;
    const int nt  = wv & 1;

    // ---- W_hh rows [r0,r0+32) -> frag-order LDS, kk = 0..31
    for (int j = 0; j < 32; ++j){
        int idx = j*TPB + tid;
        int r = idx >> 8;
        int k = (idx & 255) << 2;
        f32x4 v = *(const f32x4*)(w_hh + (size_t)(r0 + r)*HD + k);
        int kk  = k >> 5;
        int ln  = (r & 15) | (((k >> 3) & 3) << 4);
        int mtw = r >> 4;
        us4 u = { f2bf(v[0]), f2bf(v[1]), f2bf(v[2]), f2bf(v[3]) };
        *(us4*)&sAB[ ((mtw*40 + kk)*64 + ln)*8 + (k & 7) ] = u;
    }
    // ---- w_hx rows -> frag-order LDS, kk = 32..39
    for (int j = 0; j < 8; ++j){
        int idx = j*TPB + tid;
        int r = idx >> 6;
        int k = (idx & 63) << 2;
        f32x4 v = *(const f32x4*)(w_hx + (size_t)(r0 + r)*IDIM + k);
        int kk  = 32 + (k >> 5);
        int ln  = (r & 15) | (((k >> 3) & 3) << 4);
        int mtw = r >> 4;
        us4 u = { f2bf(v[0]), f2bf(v[1]), f2bf(v[2]), f2bf(v[3]) };
        *(us4*)&sAB[ ((mtw*40 + kk)*64 + ln)*8 + (k & 7) ] = u;
    }
    // ---- zero our kk=gr slice of h buffer 0 (h_init = 0)
    if (tid < 128){
        int ntz = tid >> 6, lz = tid & 63;
        us4 z = {0,0,0,0};
        size_t base = (((size_t)(gb*2 + ntz)*32 + gr)*64 + lz)*8;
        *(us4*)&g_h[0][base]     = z;
        *(us4*)&g_h[0][base + 4] = z;
    }
    f32x4 bh = *(const f32x4*)(b_h + r0 + mt*16 + ((l >> 4) << 2));

    const float* xlane = x + (size_t)(b0 + nt*16 + (l & 15)) * (SEQ*IDIM) + ((l >> 4) << 3);
    const unsigned short* sA = &sAB[ (size_t)mt * 40 * 512 ];
    const size_t hblk = (size_t)(gb*2 + nt) * 32 * 512;

    arrive(gb, gr, tid, 1);                   // init (zeroed buf0) published

    for (int t = 0; t < SEQ; ++t){
        const int rb = t & 1;
        f32x4 acc = bh;

        // ---- x-part first (independent of h): overlaps barrier latency
        const float* xp = xlane + (size_t)t*IDIM;
        #pragma unroll
        for (int kk = 0; kk < 8; ++kk){
            f32x4 v0 = *(const f32x4*)(xp + kk*32);
            f32x4 v1 = *(const f32x4*)(xp + kk*32 + 4);
            short8 bx;
            bx[0] = (short)f2bf(v0[0]); bx[1] = (short)f2bf(v0[1]);
            bx[2] = (short)f2bf(v0[2]); bx[3] = (short)f2bf(v0[3]);
            bx[4] = (short)f2bf(v1[0]); bx[5] = (short)f2bf(v1[1]);
            bx[6] = (short)f2bf(v1[2]); bx[7] = (short)f2bf(v1[3]);
            short8 a = *(const short8*)&sA[ ((32 + kk)*64 + l)*8 ];
            acc = __builtin_amdgcn_mfma_f32_16x16x32_bf16(a, bx, acc, 0, 0, 0);
        }

        wait_all(gb, tid, t + 1);             // h_t published by all groups

        // ---- recurrent part: K = 1024
        const unsigned short* hbuf = &g_h[rb][hblk];
        #pragma unroll 8
        for (int kk = 0; kk < 32; ++kk){
            short8 a = *(const short8*)&sA[ (kk*64 + l)*8 ];
            short8 b = *(const short8*)&hbuf[ (kk*64 + l)*8 ];
            acc = __builtin_amdgcn_mfma_f32_16x16x32_bf16(a, b, acc, 0, 0, 0);
        }
        float h0 = tanhf(acc[0]);
        float h1 = tanhf(acc[1]);
        float h2 = tanhf(acc[2]);
        float h3 = tanhf(acc[3]);

        int rloc = mt*16 + ((l >> 4) << 2);
        int bloc = nt*16 + (l & 15);
        int lnp  = (l & 15) | (((rloc >> 3) & 3) << 4);
        us4 hw = { f2bf(h0), f2bf(h1), f2bf(h2), f2bf(h3) };
        size_t widx = (((size_t)(gb*2 + nt)*32 + gr)*64 + lnp)*8 + (rloc & 7);
        unsigned long long hbits = __builtin_bit_cast(unsigned long long, hw);
        __builtin_nontemporal_store(hbits, (unsigned long long*)&g_h[rb ^ 1][widx]);

        if (t == SEQ-1){
            f32x4 hf = {h0, h1, h2, h3};
            *(f32x4*)&g_hfinal[b0 + bloc][r0 + rloc] = hf;
        } else {
            arrive(gb, gr, tid, t + 2);
        }
    }

    // ---- epilogue: race-free flag reset for graph replay
    __syncthreads();
    if (tid == 0){
        __hip_atomic_fetch_add(&g_done[gb*16], 1u, __ATOMIC_ACQ_REL, __HIP_MEMORY_SCOPE_AGENT);
        if (gr == 0){
            int guard = 0;
            while (__hip_atomic_load(&g_done[gb*16], __ATOMIC_ACQUIRE, __HIP_MEMORY_SCOPE_AGENT) < GRN
                   && ++guard < (1 << 22)) { }
            for (int i = 0; i < GRN; ++i)
                __hip_atomic_store(&g_flag[gb][i], 0, __ATOMIC_RELAXED, __HIP_MEMORY_SCOPE_AGENT);
            __hip_atomic_store(&g_done[gb*16], 0u, __ATOMIC_RELAXED, __HIP_MEMORY_SCOPE_AGENT);
        }
    }
}

// p = w_ph @ h_final + b_p ; out[b][c]
__global__ __launch_bounds__(TPB, 1) void proj_kernel(
    const float* __restrict__ w_ph, const float* __restrict__ b_p, float* __restrict__ out)
{
    const int b   = blockIdx.x;
    const int tid = threadIdx.x;
    const int l   = tid & 63;
    const int wv  = tid >> 6;
    __shared__ float red[4];
    f32x4 hv = *(const f32x4*)(&g_hfinal[b][0] + tid*4);
    for (int c = 0; c < NCLS; ++c){
        f32x4 wvv = *(const f32x4*)(w_ph + c*HD + tid*4);
        float s = hv[0]*wvv[0] + hv[1]*wvv[1] + hv[2]*wvv[2] + hv[3]*wvv[3];
        #pragma unroll
        for (int off = 32; off; off >>= 1) s += __shfl_down(s, off, 64);
        if (l == 0) red[wv] = s;
        __syncthreads();
        if (tid == 0) out[b*NCLS + c] = red[0] + red[1] + red[2] + red[3] + b_p[c];
        __syncthreads();
    }
}

extern "C" void kernel_launch(void* const* d_in, const int* in_sizes, int n_in,
                              void* d_out, int out_size, void* d_ws, size_t ws_size,
                              hipStream_t stream) {
    const float* x    = (const float*)d_in[0];
    const float* w_hx = (const float*)d_in[1];
    const float* w_hh = (const float*)d_in[2];
    const float* b_h  = (const float*)d_in[3];
    const float* w_ph = (const float*)d_in[4];
    const float* b_p  = (const float*)d_in[5];

    void* args[] = { (void*)&x, (void*)&w_hx, (void*)&w_hh, (void*)&b_h };
    hipError_t err = hipLaunchCooperativeKernel((void*)rnn_main, dim3(NWG), dim3(TPB),
                                                args, 0, stream);
    if (err != hipSuccess) {
        rnn_main<<<dim3(NWG), dim3(TPB), 0, stream>>>(x, w_hx, w_hh, b_h);
    }
    proj_kernel<<<dim3(BT), dim3(TPB), 0, stream>>>(w_ph, b_p, (float*)d_out);
}